// Round 19
// baseline (194.753 us; speedup 1.0000x reference)
//
#include <hip/hip_runtime.h>

// VQ nearest-neighbor: codes (64,4096,64) fp32, codebook (1024,64) fp32.
// Outputs flat in d_out: quant_codes [M*64] f32, then quant_id [M] (as f32).
//
// Round 19 = round 17 (verified, 159us) with the MFMA shape switched
// 16x16x32 -> 32x32x16 (2495 vs 2075 TF ceiling, half the MFMA insts).
// Wave = 32 queries = one 32-row A block; 32 tiles of 32 codewords;
// 12 chained MFMA per tile (3 passes x K=64/16). C/D layout per m74/m101:
// col = lane&31, row = (reg&3) + 8*(reg>>2) + 4*(lane>>5).
// A/B use the SAME k-convention (k = 16*ch + 8*(lane>>5) + e) so any
// internal k-permutation cancels. Tracking/THR/fused-gather/fixup verbatim.

#define NUM_NT 1024
#define DIM 64
#define M_TOTAL (64 * 4096)
#define NTILES32 32            // 1024 / 32 codewords per tile
#define THR 1.0e-3f            // verified r13..r18 (5x margin over ~2e-4)

typedef __attribute__((ext_vector_type(8)))  short short8;   // 8 bf16
typedef __attribute__((ext_vector_type(16))) float f32x16;

static __device__ __forceinline__ unsigned short f2bf_rne(float f) {
    unsigned u = __builtin_bit_cast(unsigned, f);
    u += 0x7FFFu + ((u >> 16) & 1u);          // round-to-nearest-even
    return (unsigned short)(u >> 16);
}
static __device__ __forceinline__ float bf2f(unsigned short h) {
    unsigned u = ((unsigned)h) << 16;
    return __builtin_bit_cast(float, u);
}

// ---------------------------------------------------------------------------
// Phase 0a: hcsq[k] = 0.5*||c_k||^2 (fixup's r1-exact math needs it);
// block 0 zeroes the worklist counter. (verbatim)
// ---------------------------------------------------------------------------
__global__ __launch_bounds__(64) void csq_kernel(const float* __restrict__ cb,
                                                 float* __restrict__ hcsq,
                                                 int* __restrict__ counter) {
    int k = blockIdx.x, d = threadIdx.x;
    if (k == 0 && d == 0) *counter = 0;
    float v = cb[k * DIM + d];
    float s = v * v;
    #pragma unroll
    for (int off = 32; off > 0; off >>= 1) s += __shfl_down(s, off);
    if (d == 0) hcsq[k] = 0.5f * s;
}

// ---------------------------------------------------------------------------
// Phase 0b: codebook -> bf16 hi/lo fragments in 32x32x16 B-layout.
// Fragment f = t*4 + ch: col n = t*32 + (lane&31), k = ch*16 + (lane>>5)*8 + e.
// ---------------------------------------------------------------------------
__global__ __launch_bounds__(256) void cb_convert32(const float* __restrict__ cb,
                                                    short8* __restrict__ bh,
                                                    short8* __restrict__ bl) {
    int gtid = blockIdx.x * 256 + threadIdx.x;   // 8192 = 128 frags x 64 lanes
    int f = gtid >> 6;
    int lane = gtid & 63;
    int t = f >> 2, ch = f & 3;
    int n  = t * 32 + (lane & 31);
    int k0 = ch * 16 + (lane >> 5) * 8;
    const float* p = cb + n * DIM + k0;
    short8 h, l;
    #pragma unroll
    for (int e = 0; e < 8; ++e) {
        float v = p[e];
        unsigned short hb = f2bf_rne(v);
        h[e] = (short)hb;
        l[e] = (short)f2bf_rne(v - bf2f(hb));
    }
    bh[f * 64 + lane] = h;
    bl[f * 64 + lane] = l;
}

// ---------------------------------------------------------------------------
// Phase 1: approx scores via 3-pass bf16 MFMA 32x32x16, 32 queries/wave,
// register double-buffer B prefetch, fmed3 second-best, fused gather/store
// epilogue, worklist flagging. (r17 semantics, new shape)
// ---------------------------------------------------------------------------
__global__ __launch_bounds__(256, 2) void vq_approx(const float* __restrict__ codes,
                                                    const short8* __restrict__ bh,
                                                    const short8* __restrict__ bl,
                                                    const float* __restrict__ cb,
                                                    float* __restrict__ out_codes,
                                                    float* __restrict__ out_ids,
                                                    int* __restrict__ worklist,
                                                    int* __restrict__ counter) {
    const int lane = threadIdx.x & 63;
    const int wv   = threadIdx.x >> 6;
    const int qb   = (blockIdx.x * 4 + wv) * 32;   // 32 queries per wave
    const int c32  = lane & 31;                    // A-row / B-col / C-col
    const int kh   = lane >> 5;                    // k-half within chunk

    // Load + split A block (negated query rows), bf16 hi/lo.
    // Chunk ch covers k = ch*16 + kh*8 + e.
    short8 ah[4], al[4];
    {
        const float* xr = codes + (size_t)(qb + c32) * DIM + kh * 8;
        #pragma unroll
        for (int ch = 0; ch < 4; ++ch) {
            #pragma unroll
            for (int e = 0; e < 8; ++e) {
                float v = -xr[ch * 16 + e];
                unsigned short hb = f2bf_rne(v);
                ah[ch][e] = (short)hb;
                al[ch][e] = (short)f2bf_rne(v - bf2f(hb));
            }
        }
    }

    float d1[16], d2[16];
    int   tb[16];
    #pragma unroll
    for (int r = 0; r < 16; ++r) { d1[r] = 3.4e38f; d2[r] = 3.4e38f; tb[r] = 0; }

    // Prefetch tile 0 B-fragments (4 chunks x hi/lo).
    short8 pbh[4], pbl[4];
    #pragma unroll
    for (int ch = 0; ch < 4; ++ch) {
        pbh[ch] = bh[ch * 64 + lane];
        pbl[ch] = bl[ch * 64 + lane];
    }

    for (int t = 0; t < NTILES32; ++t) {
        short8 vbh0 = pbh[0], vbh1 = pbh[1], vbh2 = pbh[2], vbh3 = pbh[3];
        short8 vbl0 = pbl[0], vbl1 = pbl[1], vbl2 = pbl[2], vbl3 = pbl[3];
        if (t + 1 < NTILES32) {          // issue next-tile loads before MFMA
            #pragma unroll
            for (int ch = 0; ch < 4; ++ch) {
                pbh[ch] = bh[((t + 1) * 4 + ch) * 64 + lane];
                pbl[ch] = bl[((t + 1) * 4 + ch) * 64 + lane];
            }
        }
        // score = 0.5*||c||^2 - x.c ; unit rows -> 0.5 exact to ~5e-7.
        // 12 chained MFMA (m119: chained accumulation runs at full rate).
        f32x16 acc = {0.5f, 0.5f, 0.5f, 0.5f, 0.5f, 0.5f, 0.5f, 0.5f,
                      0.5f, 0.5f, 0.5f, 0.5f, 0.5f, 0.5f, 0.5f, 0.5f};
        acc = __builtin_amdgcn_mfma_f32_32x32x16_bf16(ah[0], vbh0, acc, 0, 0, 0);
        acc = __builtin_amdgcn_mfma_f32_32x32x16_bf16(ah[1], vbh1, acc, 0, 0, 0);
        acc = __builtin_amdgcn_mfma_f32_32x32x16_bf16(ah[2], vbh2, acc, 0, 0, 0);
        acc = __builtin_amdgcn_mfma_f32_32x32x16_bf16(ah[3], vbh3, acc, 0, 0, 0);
        acc = __builtin_amdgcn_mfma_f32_32x32x16_bf16(al[0], vbh0, acc, 0, 0, 0);
        acc = __builtin_amdgcn_mfma_f32_32x32x16_bf16(al[1], vbh1, acc, 0, 0, 0);
        acc = __builtin_amdgcn_mfma_f32_32x32x16_bf16(al[2], vbh2, acc, 0, 0, 0);
        acc = __builtin_amdgcn_mfma_f32_32x32x16_bf16(al[3], vbh3, acc, 0, 0, 0);
        acc = __builtin_amdgcn_mfma_f32_32x32x16_bf16(ah[0], vbl0, acc, 0, 0, 0);
        acc = __builtin_amdgcn_mfma_f32_32x32x16_bf16(ah[1], vbl1, acc, 0, 0, 0);
        acc = __builtin_amdgcn_mfma_f32_32x32x16_bf16(ah[2], vbl2, acc, 0, 0, 0);
        acc = __builtin_amdgcn_mfma_f32_32x32x16_bf16(ah[3], vbl3, acc, 0, 0, 0);

        #pragma unroll
        for (int r = 0; r < 16; ++r) {
            float d = acc[r];
            bool take = d < d1[r];                    // first min (ties flagged)
            d2[r] = __builtin_amdgcn_fmed3f(d1[r], d2[r], d);  // min(d2,max(d1,d))
            d1[r] = fminf(d1[r], d);
            tb[r] = take ? t : tb[r];
        }
    }

    // Butterfly (5 steps, within 32-lane halves) + fused gather/store.
    // Row for reg r: (r&3) + 8*(r>>2) + 4*kh  [m74/m101 verified].
    const float4* cb4 = reinterpret_cast<const float4*>(cb);
    float4* oc4 = reinterpret_cast<float4*>(out_codes);
    #pragma unroll
    for (int r = 0; r < 16; ++r) {
        float dd1 = d1[r], dd2 = d2[r];
        int idv = tb[r] * 32 + c32;
        #pragma unroll
        for (int m = 1; m < 32; m <<= 1) {
            float d_o  = __shfl_xor(dd1, m, 64);
            int   i_o  = __shfl_xor(idv, m, 64);
            float d2_o = __shfl_xor(dd2, m, 64);
            float nd2 = fminf(fminf(dd2, d2_o), fmaxf(dd1, d_o));
            bool take = (d_o < dd1) || (d_o == dd1 && i_o < idv);
            dd1 = take ? d_o : dd1;
            idv = take ? i_o : idv;
            dd2 = nd2;
        }
        // idv/dd1/dd2 uniform within each 32-lane half; each half owns a row.
        int q = qb + (r & 3) + 8 * (r >> 2) + 4 * kh;
        if (c32 < 16)
            oc4[(size_t)q * 16 + c32] = cb4[(size_t)idv * 16 + c32];
        if (c32 == 0) {
            out_ids[q] = (float)idv;
            if (dd2 - dd1 < THR) {                       // near-tie -> rescan
                int slot = atomicAdd(counter, 1);
                worklist[slot] = q;
            }
        }
    }
}

// ---------------------------------------------------------------------------
// Fixup: one wave per worklist entry (grid-stride). Exact fp32 rescan,
// bitwise-identical math to the validated round-1 kernel; rewrites the
// code row for flagged queries. (verbatim)
// ---------------------------------------------------------------------------
__global__ __launch_bounds__(256) void vq_fixup(const float* __restrict__ codes,
                                                const float* __restrict__ cb,
                                                const float* __restrict__ hcsq,
                                                const int* __restrict__ worklist,
                                                const int* __restrict__ counter,
                                                float* __restrict__ out_codes,
                                                float* __restrict__ out_ids) {
    const int lane = threadIdx.x & 63;
    const int wid  = blockIdx.x * 4 + (threadIdx.x >> 6);
    const int nw   = gridDim.x * 4;
    const int cnt  = *counter;

    for (int w = wid; w < cnt; w += nw) {
        const int q = worklist[w];
        float x[64];
        const float4* xp = reinterpret_cast<const float4*>(codes + (size_t)q * DIM);
        #pragma unroll
        for (int i = 0; i < 16; ++i) {
            float4 v = xp[i];
            x[4*i+0] = v.x; x[4*i+1] = v.y; x[4*i+2] = v.z; x[4*i+3] = v.w;
        }
        float best = 3.4e38f; int bid = 0;
        for (int jj = 0; jj < 16; ++jj) {
            int k = jj * 64 + lane;
            const float4* cp = reinterpret_cast<const float4*>(cb + (size_t)k * DIM);
            float acc = hcsq[k];
            #pragma unroll
            for (int i = 0; i < 16; ++i) {
                float4 c = cp[i];
                acc = fmaf(-x[4*i+0], c.x, acc);
                acc = fmaf(-x[4*i+1], c.y, acc);
                acc = fmaf(-x[4*i+2], c.z, acc);
                acc = fmaf(-x[4*i+3], c.w, acc);
            }
            if (acc < best) { best = acc; bid = k; }   // strict: lowest k wins
        }
        #pragma unroll
        for (int m = 1; m < 64; m <<= 1) {
            float d_o = __shfl_xor(best, m, 64);
            int   i_o = __shfl_xor(bid, m, 64);
            bool take = (d_o < best) || (d_o == best && i_o < bid);
            best = take ? d_o : best;
            bid  = take ? i_o : bid;
        }
        int id = __shfl(bid, 0, 64);
        out_codes[(size_t)q * DIM + lane] = cb[(size_t)id * DIM + lane];
        if (lane == 0) out_ids[q] = (float)id;
    }
}

// ---------------------------------------------------------------------------
extern "C" void kernel_launch(void* const* d_in, const int* in_sizes, int n_in,
                              void* d_out, int out_size, void* d_ws, size_t ws_size,
                              hipStream_t stream) {
    const float* codes = (const float*)d_in[0];
    const float* cb    = (const float*)d_in[1];
    float* out         = (float*)d_out;

    float* out_codes = out;
    float* out_ids   = out + (size_t)M_TOTAL * DIM;

    // ws: [0,4K) hcsq | [4K,132K) bh | [132K,260K) bl | [264K) counter |
    //     [268K, 268K+1M) worklist
    float*  hcsq     = (float*)d_ws;
    short8* bh       = (short8*)((char*)d_ws + 4096);
    short8* bl       = (short8*)((char*)d_ws + 4096 + 128 * 1024);
    int*    counter  = (int*)((char*)d_ws + 264 * 1024);
    int*    worklist = (int*)((char*)d_ws + 268 * 1024);

    csq_kernel<<<NUM_NT, 64, 0, stream>>>(cb, hcsq, counter);
    cb_convert32<<<32, 256, 0, stream>>>(cb, bh, bl);
    vq_approx<<<M_TOTAL / 128, 256, 0, stream>>>(codes, bh, bl, cb,
                                                 out_codes, out_ids,
                                                 worklist, counter);
    vq_fixup<<<512, 256, 0, stream>>>(codes, cb, hcsq, worklist, counter,
                                      out_codes, out_ids);
}

// Round 20
// 164.551 us; speedup vs baseline: 1.1835x; 1.1835x over previous
//
#include <hip/hip_runtime.h>

// VQ nearest-neighbor: codes (64,4096,64) fp32, codebook (1024,64) fp32.
// Outputs flat in d_out: quant_codes [M*64] f32, then quant_id [M] (as f32).
//
// Round 20 = round 16 (verified best, 154.2us) with:
//  (a) 2-deep B-fragment prefetch ring in vq_approx (8 outstanding loads;
//      tolerates compiler-conservative waitcnt drains better than 1-deep)
//  (b) csq_kernel merged into cb_convert (one fewer launch; first 1024
//      threads compute hcsq; thread 0 zeroes the worklist counter)
// Tracking/butterfly/THR/fused-gather/fixup/rotation all r16-VERBATIM.

#define NUM_NT 1024
#define DIM 64
#define M_TOTAL (64 * 4096)
#define NTILES 64
#define THR 1.0e-3f            // verified r13..r18 (5x margin over ~2e-4)

typedef __attribute__((ext_vector_type(8))) short short8;   // 8 bf16
typedef __attribute__((ext_vector_type(4))) float f32x4;

static __device__ __forceinline__ unsigned short f2bf_rne(float f) {
    unsigned u = __builtin_bit_cast(unsigned, f);
    u += 0x7FFFu + ((u >> 16) & 1u);          // round-to-nearest-even
    return (unsigned short)(u >> 16);
}
static __device__ __forceinline__ float bf2f(unsigned short h) {
    unsigned u = ((unsigned)h) << 16;
    return __builtin_bit_cast(float, u);
}

// ---------------------------------------------------------------------------
// Phase 0 (merged): codebook -> bf16 hi/lo fragments in MFMA B-layout;
// first 1024 threads also compute hcsq[row] = 0.5*||c_row||^2 (for fixup);
// thread 0 zeroes the worklist counter.
// ---------------------------------------------------------------------------
__global__ __launch_bounds__(256) void cb_convert(const float* __restrict__ cb,
                                                  short8* __restrict__ bh,
                                                  short8* __restrict__ bl,
                                                  float* __restrict__ hcsq,
                                                  int* __restrict__ counter) {
    int gtid = blockIdx.x * 256 + threadIdx.x;   // 8192 = 128 frags x 64 lanes
    if (gtid == 0) *counter = 0;
    int f = gtid >> 6;
    int lane = gtid & 63;
    int t = f >> 1, kk = f & 1;
    int n = t * 16 + (lane & 15);
    int k0 = kk * 32 + 8 * (lane >> 4);
    const float* p = cb + n * DIM + k0;
    short8 h, l;
    #pragma unroll
    for (int e = 0; e < 8; ++e) {
        float v = p[e];
        unsigned short hb = f2bf_rne(v);
        h[e] = (short)hb;
        l[e] = (short)f2bf_rne(v - bf2f(hb));
    }
    bh[f * 64 + lane] = h;
    bl[f * 64 + lane] = l;

    if (gtid < NUM_NT) {                       // one row per thread
        const float4* rp = reinterpret_cast<const float4*>(cb + (size_t)gtid * DIM);
        float s = 0.0f;
        #pragma unroll
        for (int i = 0; i < 16; ++i) {
            float4 v = rp[i];
            s += v.x * v.x + v.y * v.y + v.z * v.z + v.w * v.w;
        }
        hcsq[gtid] = 0.5f * s;
    }
}

// ---------------------------------------------------------------------------
// Phase 1: approx scores via 3-pass bf16 MFMA, 64 queries/wave, 2-deep
// register prefetch ring for B fragments, fmed3 second-best, per-wave
// tile-phase rotation, fused gather/store epilogue. (r16 + 2-deep ring)
// ---------------------------------------------------------------------------
__global__ __launch_bounds__(256, 2) void vq_approx(const float* __restrict__ codes,
                                                    const short8* __restrict__ bh,
                                                    const short8* __restrict__ bl,
                                                    const float* __restrict__ cb,
                                                    float* __restrict__ out_codes,
                                                    float* __restrict__ out_ids,
                                                    int* __restrict__ worklist,
                                                    int* __restrict__ counter) {
    const int lane = threadIdx.x & 63;
    const int wv   = threadIdx.x >> 6;
    const int gw   = blockIdx.x * 4 + wv;          // global wave id
    const int qb   = gw * 64;                      // 64 queries per wave
    const int c16  = lane & 15;
    const int kg   = lane >> 4;
    const int phase = (gw & 3) * 16;               // tile-phase rotation

    short8 ah[4][2], al[4][2];
    #pragma unroll
    for (int s = 0; s < 4; ++s) {
        const float* xr = codes + (size_t)(qb + s * 16 + c16) * DIM + kg * 8;
        #pragma unroll
        for (int e = 0; e < 8; ++e) {
            float v = -xr[e];
            unsigned short hb = f2bf_rne(v);
            ah[s][0][e] = (short)hb;
            al[s][0][e] = (short)f2bf_rne(v - bf2f(hb));
            float w = -xr[32 + e];
            unsigned short hw = f2bf_rne(w);
            ah[s][1][e] = (short)hw;
            al[s][1][e] = (short)f2bf_rne(w - bf2f(hw));
        }
    }

    float d1[16], d2[16];
    int   tb[16];
    #pragma unroll
    for (int r = 0; r < 16; ++r) { d1[r] = 3.4e38f; d2[r] = 3.4e38f; tb[r] = 0; }

    // 2-deep prefetch ring: p0 = tile(phase), p1 = tile(phase+1).
    const int t0 = phase;
    const int t1 = (phase + 1) & (NTILES - 1);
    short8 p0h0 = bh[(t0 * 2 + 0) * 64 + lane], p0l0 = bl[(t0 * 2 + 0) * 64 + lane];
    short8 p0h1 = bh[(t0 * 2 + 1) * 64 + lane], p0l1 = bl[(t0 * 2 + 1) * 64 + lane];
    short8 p1h0 = bh[(t1 * 2 + 0) * 64 + lane], p1l0 = bl[(t1 * 2 + 0) * 64 + lane];
    short8 p1h1 = bh[(t1 * 2 + 1) * 64 + lane], p1l1 = bl[(t1 * 2 + 1) * 64 + lane];

    for (int tt = 0; tt < NTILES; ++tt) {
        const int t = (tt + phase) & (NTILES - 1);   // rotated tile index
        short8 vh0 = p0h0, vl0 = p0l0, vh1 = p0h1, vl1 = p0l1;
        p0h0 = p1h0; p0l0 = p1l0; p0h1 = p1h1; p0l1 = p1l1;
        if (tt + 2 < NTILES) {           // issue tile(t+2) loads before MFMA
            const int tn = (tt + 2 + phase) & (NTILES - 1);
            p1h0 = bh[(tn * 2 + 0) * 64 + lane];
            p1l0 = bl[(tn * 2 + 0) * 64 + lane];
            p1h1 = bh[(tn * 2 + 1) * 64 + lane];
            p1l1 = bl[(tn * 2 + 1) * 64 + lane];
        }
        #pragma unroll
        for (int s = 0; s < 4; ++s) {
            // score = 0.5*||c||^2 - x.c ; rows unit-norm so 0.5 exact ~5e-7
            f32x4 acc = {0.5f, 0.5f, 0.5f, 0.5f};
            acc = __builtin_amdgcn_mfma_f32_16x16x32_bf16(ah[s][0], vh0, acc, 0, 0, 0);
            acc = __builtin_amdgcn_mfma_f32_16x16x32_bf16(al[s][0], vh0, acc, 0, 0, 0);
            acc = __builtin_amdgcn_mfma_f32_16x16x32_bf16(ah[s][0], vl0, acc, 0, 0, 0);
            acc = __builtin_amdgcn_mfma_f32_16x16x32_bf16(ah[s][1], vh1, acc, 0, 0, 0);
            acc = __builtin_amdgcn_mfma_f32_16x16x32_bf16(al[s][1], vh1, acc, 0, 0, 0);
            acc = __builtin_amdgcn_mfma_f32_16x16x32_bf16(ah[s][1], vl1, acc, 0, 0, 0);
            #pragma unroll
            for (int rr = 0; rr < 4; ++rr) {
                float d = acc[rr];
                int r = s * 4 + rr;
                bool take = d < d1[r];                    // first min (ties flagged)
                d2[r] = __builtin_amdgcn_fmed3f(d1[r], d2[r], d);  // min(d2,max(d1,d))
                d1[r] = fminf(d1[r], d);
                tb[r] = take ? t : tb[r];
            }
        }
    }

    // Butterfly + fused gather/store epilogue. (r16-verbatim)
    const float4* cb4 = reinterpret_cast<const float4*>(cb);
    float4* oc4 = reinterpret_cast<float4*>(out_codes);
    #pragma unroll
    for (int r = 0; r < 16; ++r) {
        float dd1 = d1[r], dd2 = d2[r];
        int idv = tb[r] * 16 + c16;
        #pragma unroll
        for (int m = 1; m < 16; m <<= 1) {
            float d_o  = __shfl_xor(dd1, m, 64);
            int   i_o  = __shfl_xor(idv, m, 64);
            float d2_o = __shfl_xor(dd2, m, 64);
            float nd2 = fminf(fminf(dd2, d2_o), fmaxf(dd1, d_o));
            bool take = (d_o < dd1) || (d_o == dd1 && i_o < idv);
            dd1 = take ? d_o : dd1;
            idv = take ? i_o : idv;
            dd2 = nd2;
        }
        int q = qb + (r >> 2) * 16 + kg * 4 + (r & 3);
        oc4[(size_t)q * 16 + c16] = cb4[(size_t)idv * 16 + c16];
        if (c16 == 0) {
            out_ids[q] = (float)idv;
            if (dd2 - dd1 < THR) {                       // near-tie -> rescan
                int slot = atomicAdd(counter, 1);
                worklist[slot] = q;
            }
        }
    }
}

// ---------------------------------------------------------------------------
// Fixup: one wave per worklist entry (grid-stride). Exact fp32 rescan,
// bitwise-identical math to the validated round-1 kernel; rewrites the
// code row for flagged queries. (r16-verbatim)
// ---------------------------------------------------------------------------
__global__ __launch_bounds__(256) void vq_fixup(const float* __restrict__ codes,
                                                const float* __restrict__ cb,
                                                const float* __restrict__ hcsq,
                                                const int* __restrict__ worklist,
                                                const int* __restrict__ counter,
                                                float* __restrict__ out_codes,
                                                float* __restrict__ out_ids) {
    const int lane = threadIdx.x & 63;
    const int wid  = blockIdx.x * 4 + (threadIdx.x >> 6);
    const int nw   = gridDim.x * 4;
    const int cnt  = *counter;

    for (int w = wid; w < cnt; w += nw) {
        const int q = worklist[w];
        float x[64];
        const float4* xp = reinterpret_cast<const float4*>(codes + (size_t)q * DIM);
        #pragma unroll
        for (int i = 0; i < 16; ++i) {
            float4 v = xp[i];
            x[4*i+0] = v.x; x[4*i+1] = v.y; x[4*i+2] = v.z; x[4*i+3] = v.w;
        }
        float best = 3.4e38f; int bid = 0;
        for (int jj = 0; jj < 16; ++jj) {
            int k = jj * 64 + lane;
            const float4* cp = reinterpret_cast<const float4*>(cb + (size_t)k * DIM);
            float acc = hcsq[k];
            #pragma unroll
            for (int i = 0; i < 16; ++i) {
                float4 c = cp[i];
                acc = fmaf(-x[4*i+0], c.x, acc);
                acc = fmaf(-x[4*i+1], c.y, acc);
                acc = fmaf(-x[4*i+2], c.z, acc);
                acc = fmaf(-x[4*i+3], c.w, acc);
            }
            if (acc < best) { best = acc; bid = k; }   // strict: lowest k wins
        }
        #pragma unroll
        for (int m = 1; m < 64; m <<= 1) {
            float d_o = __shfl_xor(best, m, 64);
            int   i_o = __shfl_xor(bid, m, 64);
            bool take = (d_o < best) || (d_o == best && i_o < bid);
            best = take ? d_o : best;
            bid  = take ? i_o : bid;
        }
        int id = __shfl(bid, 0, 64);
        out_codes[(size_t)q * DIM + lane] = cb[(size_t)id * DIM + lane];
        if (lane == 0) out_ids[q] = (float)id;
    }
}

// ---------------------------------------------------------------------------
extern "C" void kernel_launch(void* const* d_in, const int* in_sizes, int n_in,
                              void* d_out, int out_size, void* d_ws, size_t ws_size,
                              hipStream_t stream) {
    const float* codes = (const float*)d_in[0];
    const float* cb    = (const float*)d_in[1];
    float* out         = (float*)d_out;

    float* out_codes = out;
    float* out_ids   = out + (size_t)M_TOTAL * DIM;

    // ws: [0,4K) hcsq | [4K,132K) bh | [132K,260K) bl | [264K) counter |
    //     [268K, 268K+1M) worklist
    float*  hcsq     = (float*)d_ws;
    short8* bh       = (short8*)((char*)d_ws + 4096);
    short8* bl       = (short8*)((char*)d_ws + 4096 + 128 * 1024);
    int*    counter  = (int*)((char*)d_ws + 264 * 1024);
    int*    worklist = (int*)((char*)d_ws + 268 * 1024);

    cb_convert<<<32, 256, 0, stream>>>(cb, bh, bl, hcsq, counter);
    vq_approx<<<M_TOTAL / 256, 256, 0, stream>>>(codes, bh, bl, cb,
                                                 out_codes, out_ids,
                                                 worklist, counter);
    vq_fixup<<<512, 256, 0, stream>>>(codes, cb, hcsq, worklist, counter,
                                      out_codes, out_ids);
}

// Round 21
// 152.316 us; speedup vs baseline: 1.2786x; 1.0803x over previous
//
#include <hip/hip_runtime.h>

// VQ nearest-neighbor: codes (64,4096,64) fp32, codebook (1024,64) fp32.
// Outputs flat in d_out: quant_codes [M*64] f32, then quant_id [M] (as f32).
//
// Round 21 = round 16 (verified best, 154.2us) + verified tail trims:
//  (a) 1-deep B prefetch restored (r20's 2-deep ring regressed: VGPR 92,
//      occ 20%, approx +20us)
//  (b) csq merged into cb_convert (verified in r20; one fewer dispatch)
//  (c) THR 1e-3 -> 5e-4 (2.5x margin over ~2e-4 worst-case gap error;
//      halves the cnt-linear fixup cost)
// approx compute/tracking/butterfly/fused-gather, fixup math: r16-VERBATIM.

#define NUM_NT 1024
#define DIM 64
#define M_TOTAL (64 * 4096)
#define NTILES 64
#define THR 5.0e-4f            // 2.5x margin over ~2e-4 worst-case gap error

typedef __attribute__((ext_vector_type(8))) short short8;   // 8 bf16
typedef __attribute__((ext_vector_type(4))) float f32x4;

static __device__ __forceinline__ unsigned short f2bf_rne(float f) {
    unsigned u = __builtin_bit_cast(unsigned, f);
    u += 0x7FFFu + ((u >> 16) & 1u);          // round-to-nearest-even
    return (unsigned short)(u >> 16);
}
static __device__ __forceinline__ float bf2f(unsigned short h) {
    unsigned u = ((unsigned)h) << 16;
    return __builtin_bit_cast(float, u);
}

// ---------------------------------------------------------------------------
// Phase 0 (merged, verified r20): codebook -> bf16 hi/lo fragments in MFMA
// B-layout; first 1024 threads also compute hcsq[row] = 0.5*||c_row||^2
// (fixup's exact rescan uses it); thread 0 zeroes the worklist counter.
// ---------------------------------------------------------------------------
__global__ __launch_bounds__(256) void cb_convert(const float* __restrict__ cb,
                                                  short8* __restrict__ bh,
                                                  short8* __restrict__ bl,
                                                  float* __restrict__ hcsq,
                                                  int* __restrict__ counter) {
    int gtid = blockIdx.x * 256 + threadIdx.x;   // 8192 = 128 frags x 64 lanes
    if (gtid == 0) *counter = 0;
    int f = gtid >> 6;
    int lane = gtid & 63;
    int t = f >> 1, kk = f & 1;
    int n = t * 16 + (lane & 15);
    int k0 = kk * 32 + 8 * (lane >> 4);
    const float* p = cb + n * DIM + k0;
    short8 h, l;
    #pragma unroll
    for (int e = 0; e < 8; ++e) {
        float v = p[e];
        unsigned short hb = f2bf_rne(v);
        h[e] = (short)hb;
        l[e] = (short)f2bf_rne(v - bf2f(hb));
    }
    bh[f * 64 + lane] = h;
    bl[f * 64 + lane] = l;

    if (gtid < NUM_NT) {                       // one row per thread
        const float4* rp = reinterpret_cast<const float4*>(cb + (size_t)gtid * DIM);
        float s = 0.0f;
        #pragma unroll
        for (int i = 0; i < 16; ++i) {
            float4 v = rp[i];
            s += v.x * v.x + v.y * v.y + v.z * v.z + v.w * v.w;
        }
        hcsq[gtid] = 0.5f * s;
    }
}

// ---------------------------------------------------------------------------
// Phase 1: approx scores via 3-pass bf16 MFMA, 64 queries/wave, 1-deep
// register double-buffer B prefetch, fmed3 second-best, per-wave tile-phase
// rotation, fused gather/store epilogue. (r16-VERBATIM)
// ---------------------------------------------------------------------------
__global__ __launch_bounds__(256, 2) void vq_approx(const float* __restrict__ codes,
                                                    const short8* __restrict__ bh,
                                                    const short8* __restrict__ bl,
                                                    const float* __restrict__ cb,
                                                    float* __restrict__ out_codes,
                                                    float* __restrict__ out_ids,
                                                    int* __restrict__ worklist,
                                                    int* __restrict__ counter) {
    const int lane = threadIdx.x & 63;
    const int wv   = threadIdx.x >> 6;
    const int gw   = blockIdx.x * 4 + wv;          // global wave id
    const int qb   = gw * 64;                      // 64 queries per wave
    const int c16  = lane & 15;
    const int kg   = lane >> 4;
    const int phase = (gw & 3) * 16;               // tile-phase rotation

    short8 ah[4][2], al[4][2];
    #pragma unroll
    for (int s = 0; s < 4; ++s) {
        const float* xr = codes + (size_t)(qb + s * 16 + c16) * DIM + kg * 8;
        #pragma unroll
        for (int e = 0; e < 8; ++e) {
            float v = -xr[e];
            unsigned short hb = f2bf_rne(v);
            ah[s][0][e] = (short)hb;
            al[s][0][e] = (short)f2bf_rne(v - bf2f(hb));
            float w = -xr[32 + e];
            unsigned short hw = f2bf_rne(w);
            ah[s][1][e] = (short)hw;
            al[s][1][e] = (short)f2bf_rne(w - bf2f(hw));
        }
    }

    float d1[16], d2[16];
    int   tb[16];
    #pragma unroll
    for (int r = 0; r < 16; ++r) { d1[r] = 3.4e38f; d2[r] = 3.4e38f; tb[r] = 0; }

    short8 pvh0 = bh[(phase * 2 + 0) * 64 + lane];
    short8 pvl0 = bl[(phase * 2 + 0) * 64 + lane];
    short8 pvh1 = bh[(phase * 2 + 1) * 64 + lane];
    short8 pvl1 = bl[(phase * 2 + 1) * 64 + lane];

    for (int tt = 0; tt < NTILES; ++tt) {
        const int t = (tt + phase) & (NTILES - 1);   // rotated tile index
        short8 vh0 = pvh0, vl0 = pvl0, vh1 = pvh1, vl1 = pvl1;
        if (tt + 1 < NTILES) {            // issue next-tile loads before MFMA
            const int tn = (tt + 1 + phase) & (NTILES - 1);
            pvh0 = bh[(tn * 2 + 0) * 64 + lane];
            pvl0 = bl[(tn * 2 + 0) * 64 + lane];
            pvh1 = bh[(tn * 2 + 1) * 64 + lane];
            pvl1 = bl[(tn * 2 + 1) * 64 + lane];
        }
        #pragma unroll
        for (int s = 0; s < 4; ++s) {
            // score = 0.5*||c||^2 - x.c ; rows unit-norm so 0.5 exact ~5e-7
            f32x4 acc = {0.5f, 0.5f, 0.5f, 0.5f};
            acc = __builtin_amdgcn_mfma_f32_16x16x32_bf16(ah[s][0], vh0, acc, 0, 0, 0);
            acc = __builtin_amdgcn_mfma_f32_16x16x32_bf16(al[s][0], vh0, acc, 0, 0, 0);
            acc = __builtin_amdgcn_mfma_f32_16x16x32_bf16(ah[s][0], vl0, acc, 0, 0, 0);
            acc = __builtin_amdgcn_mfma_f32_16x16x32_bf16(ah[s][1], vh1, acc, 0, 0, 0);
            acc = __builtin_amdgcn_mfma_f32_16x16x32_bf16(al[s][1], vh1, acc, 0, 0, 0);
            acc = __builtin_amdgcn_mfma_f32_16x16x32_bf16(ah[s][1], vl1, acc, 0, 0, 0);
            #pragma unroll
            for (int rr = 0; rr < 4; ++rr) {
                float d = acc[rr];
                int r = s * 4 + rr;
                bool take = d < d1[r];                    // first min (ties flagged)
                d2[r] = __builtin_amdgcn_fmed3f(d1[r], d2[r], d);  // min(d2,max(d1,d))
                d1[r] = fminf(d1[r], d);
                tb[r] = take ? t : tb[r];
            }
        }
    }

    // Butterfly + fused gather/store epilogue. (r16-verbatim)
    const float4* cb4 = reinterpret_cast<const float4*>(cb);
    float4* oc4 = reinterpret_cast<float4*>(out_codes);
    #pragma unroll
    for (int r = 0; r < 16; ++r) {
        float dd1 = d1[r], dd2 = d2[r];
        int idv = tb[r] * 16 + c16;
        #pragma unroll
        for (int m = 1; m < 16; m <<= 1) {
            float d_o  = __shfl_xor(dd1, m, 64);
            int   i_o  = __shfl_xor(idv, m, 64);
            float d2_o = __shfl_xor(dd2, m, 64);
            float nd2 = fminf(fminf(dd2, d2_o), fmaxf(dd1, d_o));
            bool take = (d_o < dd1) || (d_o == dd1 && i_o < idv);
            dd1 = take ? d_o : dd1;
            idv = take ? i_o : idv;
            dd2 = nd2;
        }
        int q = qb + (r >> 2) * 16 + kg * 4 + (r & 3);
        oc4[(size_t)q * 16 + c16] = cb4[(size_t)idv * 16 + c16];
        if (c16 == 0) {
            out_ids[q] = (float)idv;
            if (dd2 - dd1 < THR) {                       // near-tie -> rescan
                int slot = atomicAdd(counter, 1);
                worklist[slot] = q;
            }
        }
    }
}

// ---------------------------------------------------------------------------
// Fixup: one wave per worklist entry (grid-stride). Exact fp32 rescan,
// bitwise-identical math to the validated round-1 kernel; rewrites the
// code row for flagged queries. (r16-verbatim)
// ---------------------------------------------------------------------------
__global__ __launch_bounds__(256) void vq_fixup(const float* __restrict__ codes,
                                                const float* __restrict__ cb,
                                                const float* __restrict__ hcsq,
                                                const int* __restrict__ worklist,
                                                const int* __restrict__ counter,
                                                float* __restrict__ out_codes,
                                                float* __restrict__ out_ids) {
    const int lane = threadIdx.x & 63;
    const int wid  = blockIdx.x * 4 + (threadIdx.x >> 6);
    const int nw   = gridDim.x * 4;
    const int cnt  = *counter;

    for (int w = wid; w < cnt; w += nw) {
        const int q = worklist[w];
        float x[64];
        const float4* xp = reinterpret_cast<const float4*>(codes + (size_t)q * DIM);
        #pragma unroll
        for (int i = 0; i < 16; ++i) {
            float4 v = xp[i];
            x[4*i+0] = v.x; x[4*i+1] = v.y; x[4*i+2] = v.z; x[4*i+3] = v.w;
        }
        float best = 3.4e38f; int bid = 0;
        for (int jj = 0; jj < 16; ++jj) {
            int k = jj * 64 + lane;
            const float4* cp = reinterpret_cast<const float4*>(cb + (size_t)k * DIM);
            float acc = hcsq[k];
            #pragma unroll
            for (int i = 0; i < 16; ++i) {
                float4 c = cp[i];
                acc = fmaf(-x[4*i+0], c.x, acc);
                acc = fmaf(-x[4*i+1], c.y, acc);
                acc = fmaf(-x[4*i+2], c.z, acc);
                acc = fmaf(-x[4*i+3], c.w, acc);
            }
            if (acc < best) { best = acc; bid = k; }   // strict: lowest k wins
        }
        #pragma unroll
        for (int m = 1; m < 64; m <<= 1) {
            float d_o = __shfl_xor(best, m, 64);
            int   i_o = __shfl_xor(bid, m, 64);
            bool take = (d_o < best) || (d_o == best && i_o < bid);
            best = take ? d_o : best;
            bid  = take ? i_o : bid;
        }
        int id = __shfl(bid, 0, 64);
        out_codes[(size_t)q * DIM + lane] = cb[(size_t)id * DIM + lane];
        if (lane == 0) out_ids[q] = (float)id;
    }
}

// ---------------------------------------------------------------------------
extern "C" void kernel_launch(void* const* d_in, const int* in_sizes, int n_in,
                              void* d_out, int out_size, void* d_ws, size_t ws_size,
                              hipStream_t stream) {
    const float* codes = (const float*)d_in[0];
    const float* cb    = (const float*)d_in[1];
    float* out         = (float*)d_out;

    float* out_codes = out;
    float* out_ids   = out + (size_t)M_TOTAL * DIM;

    // ws: [0,4K) hcsq | [4K,132K) bh | [132K,260K) bl | [264K) counter |
    //     [268K, 268K+1M) worklist
    float*  hcsq     = (float*)d_ws;
    short8* bh       = (short8*)((char*)d_ws + 4096);
    short8* bl       = (short8*)((char*)d_ws + 4096 + 128 * 1024);
    int*    counter  = (int*)((char*)d_ws + 264 * 1024);
    int*    worklist = (int*)((char*)d_ws + 268 * 1024);

    cb_convert<<<32, 256, 0, stream>>>(cb, bh, bl, hcsq, counter);
    vq_approx<<<M_TOTAL / 256, 256, 0, stream>>>(codes, bh, bl, cb,
                                                 out_codes, out_ids,
                                                 worklist, counter);
    vq_fixup<<<512, 256, 0, stream>>>(codes, cb, hcsq, worklist, counter,
                                      out_codes, out_ids);
}